// Round 4
// baseline (228.813 us; speedup 1.0000x reference)
//
#include <hip/hip_runtime.h>
#include <math.h>

#define NROW 1024
#define BATCH 4
#define NT 16
#define NTRI 136             // 16*17/2
#define NBLK (BATCH * NTRI)  // 544

__device__ __forceinline__ float tanh_fast(float x) {
    const float e = __expf(2.f * fabsf(x));
    const float r = 1.f - 2.f / (e + 1.f);
    return copysignf(r, x);
}

// Single self-contained kernel: each block computes features for its two
// 64-row tiles (redundantly across blocks), then the pairwise scores.
// LDS: FT 34816 + X 12288 + H 4096 + P 2048 = 53248 B.
__global__ __launch_bounds__(256) void fused_scorer(
    const float* __restrict__ emb,   // [4096][128]
    const float* __restrict__ temp,  // [4096][64]
    const float* __restrict__ W1,    // [192][64]
    const float* __restrict__ b1,    // [64]
    const float* __restrict__ W2,    // [64][32]
    const float* __restrict__ b2,    // [32]
    const float* __restrict__ W3,    // [64][32]
    const float* __restrict__ b3,    // [32]
    const float* __restrict__ W4,    // [32]
    const float* __restrict__ b4,    // [1]
    float* __restrict__ out)         // [4][1024][1024]
{
    // FT[0]=hi(I rows), FT[1]=hjb(I rows), FT[2]=hi(J rows), FT[3]=hjb(J rows)
    // layout [k][row] (transposed), stride 68 to dodge bank conflicts.
    __shared__ __align__(16) float FT[4][32][68];
    __shared__ __align__(16) float X[16][192];
    __shared__ __align__(16) float H[16][64];
    __shared__ __align__(16) float P[16][32];

    const int t = threadIdx.x;
    const int bx = blockIdx.x;
    const int b = bx / NTRI;
    int tidx = bx % NTRI;
    int ti = 0;
    while (tidx >= NT - ti) { tidx -= NT - ti; ++ti; }
    const int tj = ti + tidx;

    // ================= feature phase: 8 chunks of 16 rows =================
    for (int ch = 0; ch < 8; ++ch) {
        const int tile = (ch < 4) ? ti : tj;  // 0-3: I-tile rows, 4-7: J-tile rows
        const int sub = ch & 3;
        const int half = ch >> 2;
        const int rowbase = b * NROW + tile * 64 + sub * 16;  // global row index

        // ---- stage X[16][192] (emb 32 f4/row + temp 16 f4/row = 768 f4) ----
#pragma unroll
        for (int rep = 0; rep < 3; ++rep) {
            const int idx = t + rep * 256;  // 0..767
            const int r = idx / 48;
            const int c = idx - r * 48;
            float4 v;
            if (c < 32) v = reinterpret_cast<const float4*>(emb)[(size_t)(rowbase + r) * 32 + c];
            else        v = reinterpret_cast<const float4*>(temp)[(size_t)(rowbase + r) * 16 + (c - 32)];
            *reinterpret_cast<float4*>(&X[r][c * 4]) = v;
        }
        __syncthreads();

        // ---- L1: [16x192]@[192x64]+b1 -> relu -> H. 4 rows/thread ----
        {
            const int o = t & 63;
            const int r0 = t >> 6;  // 0..3
            float s0 = b1[o], s1 = s0, s2 = s0, s3 = s0;
#pragma unroll 4
            for (int k4 = 0; k4 < 48; ++k4) {
                const float4 x0 = *reinterpret_cast<const float4*>(&X[r0][k4 * 4]);
                const float4 x1 = *reinterpret_cast<const float4*>(&X[r0 + 4][k4 * 4]);
                const float4 x2 = *reinterpret_cast<const float4*>(&X[r0 + 8][k4 * 4]);
                const float4 x3 = *reinterpret_cast<const float4*>(&X[r0 + 12][k4 * 4]);
                const float w0 = W1[(k4 * 4 + 0) * 64 + o];
                const float w1 = W1[(k4 * 4 + 1) * 64 + o];
                const float w2 = W1[(k4 * 4 + 2) * 64 + o];
                const float w3 = W1[(k4 * 4 + 3) * 64 + o];
                s0 = fmaf(x0.w, w3, fmaf(x0.z, w2, fmaf(x0.y, w1, fmaf(x0.x, w0, s0))));
                s1 = fmaf(x1.w, w3, fmaf(x1.z, w2, fmaf(x1.y, w1, fmaf(x1.x, w0, s1))));
                s2 = fmaf(x2.w, w3, fmaf(x2.z, w2, fmaf(x2.y, w1, fmaf(x2.x, w0, s2))));
                s3 = fmaf(x3.w, w3, fmaf(x3.z, w2, fmaf(x3.y, w1, fmaf(x3.x, w0, s3))));
            }
            H[r0][o]      = fmaxf(s0, 0.f);
            H[r0 + 4][o]  = fmaxf(s1, 0.f);
            H[r0 + 8][o]  = fmaxf(s2, 0.f);
            H[r0 + 12][o] = fmaxf(s3, 0.f);
        }
        __syncthreads();

        // ---- L2: [16x64]@[64x32]+b2 -> relu -> P. 2 rows/thread ----
        {
            const int o2 = t & 31;
            const int r8 = t >> 5;  // 0..7
#pragma unroll
            for (int rr = 0; rr < 2; ++rr) {
                const int r = r8 + rr * 8;
                float s = b2[o2];
#pragma unroll 8
                for (int k = 0; k < 64; ++k) s += H[r][k] * W2[k * 32 + o2];
                P[r][o2] = fmaxf(s, 0.f);
            }
        }
        __syncthreads();

        // ---- L3: hi = P@W3[:32]; hjb = P@W3[32:]+b3 -> FT (transposed) ----
        {
            const int o2 = t & 31;
            const int r8 = t >> 5;
#pragma unroll
            for (int rr = 0; rr < 2; ++rr) {
                const int r = r8 + rr * 8;
                float sa = 0.f, sb = b3[o2];
#pragma unroll 8
                for (int k = 0; k < 32; ++k) {
                    const float p = P[r][k];
                    sa += p * W3[k * 32 + o2];
                    sb += p * W3[(32 + k) * 32 + o2];
                }
                FT[half * 2 + 0][o2][sub * 16 + r] = sa;
                FT[half * 2 + 1][o2][sub * 16 + r] = sb;
            }
        }
        __syncthreads();
    }

    // ================= pair phase =================
    const int ty = t >> 4;  // 0..15
    const int tx = t & 15;  // 0..15

    float F[4][4] = {};  // pre-act of z(i0+a, j0+c)
    float G[4][4] = {};  // pre-act of z(j0+c, i0+a)
#pragma unroll
    for (int k = 0; k < 32; ++k) {
        const float w = W4[k];
        const float4 ai = *reinterpret_cast<const float4*>(&FT[0][k][4 * ty]);  // hi  I
        const float4 bi = *reinterpret_cast<const float4*>(&FT[1][k][4 * ty]);  // hjb I
        const float4 aj = *reinterpret_cast<const float4*>(&FT[2][k][4 * tx]);  // hi  J
        const float4 bj = *reinterpret_cast<const float4*>(&FT[3][k][4 * tx]);  // hjb J
        const float av[4] = {ai.x, ai.y, ai.z, ai.w};
        const float bw[4] = {bi.x, bi.y, bi.z, bi.w};
        const float aw[4] = {aj.x, aj.y, aj.z, aj.w};
        const float bv[4] = {bj.x, bj.y, bj.z, bj.w};
#pragma unroll
        for (int a = 0; a < 4; ++a)
#pragma unroll
            for (int c = 0; c < 4; ++c) {
                F[a][c] = fmaf(fmaxf(av[a] + bv[c], 0.f), w, F[a][c]);
                G[a][c] = fmaf(fmaxf(aw[c] + bw[a], 0.f), w, G[a][c]);
            }
    }

    const float bb = *b4;
    float S[4][4];
#pragma unroll
    for (int a = 0; a < 4; ++a)
#pragma unroll
        for (int c = 0; c < 4; ++c)
            S[a][c] = 0.5f * (tanh_fast(F[a][c] + bb) + tanh_fast(G[a][c] + bb));

    float* outb = out + (size_t)b * (NROW * NROW);
    const int i0 = ti * 64 + 4 * ty;
    const int j0 = tj * 64 + 4 * tx;
#pragma unroll
    for (int a = 0; a < 4; ++a) {
        float4 v = make_float4(S[a][0], S[a][1], S[a][2], S[a][3]);
        *reinterpret_cast<float4*>(&outb[(size_t)(i0 + a) * NROW + j0]) = v;
    }
    if (ti != tj) {
#pragma unroll
        for (int c = 0; c < 4; ++c) {
            float4 v = make_float4(S[0][c], S[1][c], S[2][c], S[3][c]);
            *reinterpret_cast<float4*>(&outb[(size_t)(j0 + c) * NROW + i0]) = v;
        }
    }
}

extern "C" void kernel_launch(void* const* d_in, const int* in_sizes, int n_in,
                              void* d_out, int out_size, void* d_ws, size_t ws_size,
                              hipStream_t stream) {
    const float* emb  = (const float*)d_in[0];
    const float* temp = (const float*)d_in[1];
    const float* W1   = (const float*)d_in[2];
    const float* b1   = (const float*)d_in[3];
    const float* W2   = (const float*)d_in[4];
    const float* b2   = (const float*)d_in[5];
    const float* W3   = (const float*)d_in[6];
    const float* b3   = (const float*)d_in[7];
    const float* W4   = (const float*)d_in[8];
    const float* b4   = (const float*)d_in[9];
    float* out = (float*)d_out;

    hipLaunchKernelGGL(fused_scorer, dim3(NBLK), dim3(256), 0, stream,
                       emb, temp, W1, b1, W2, b2, W3, b3, W4, b4, out);
}